// Round 9
// baseline (238.976 us; speedup 1.0000x reference)
//
#include <hip/hip_runtime.h>
#include <stdint.h>
#include <stddef.h>

typedef __bf16 bf16;
typedef __bf16 bf16x8 __attribute__((ext_vector_type(8)));
typedef float f32x4 __attribute__((ext_vector_type(4)));

// ---------------------------------------------------------------------------
// async global->LDS, 16B per lane. LDS dest is wave-uniform base + lane*16.
// ---------------------------------------------------------------------------
__device__ __forceinline__ void global_to_lds16(const void* g, void* l) {
  const __attribute__((address_space(1))) unsigned* gp =
      reinterpret_cast<const __attribute__((address_space(1))) unsigned*>(
          reinterpret_cast<uintptr_t>(g));
  __attribute__((address_space(3))) unsigned* lp =
      reinterpret_cast<__attribute__((address_space(3))) unsigned*>(
          reinterpret_cast<uintptr_t>(l));
  __builtin_amdgcn_global_load_lds(gp, lp, 16, 0, 0);
}

// ---------------------------------------------------------------------------
// XCD-aware tile swizzle for 64-tile (8x8) GEMMs.
// ---------------------------------------------------------------------------
__device__ __forceinline__ void tile8x8_swizzle(int t, int& bx, int& by) {
  bx = (((t >> 3) & 1) << 2) | (t & 3);
  by = (((t >> 4) & 3) << 1) | ((t >> 2) & 1);
}

// ---------------------------------------------------------------------------
// 128x128-tile NT GEMM body, BK=64, PING-PONG double-buffered LDS (64 KB).
// R0 PROVEN BODY (197 us baseline) -- byte-for-byte unchanged.
// ---------------------------------------------------------------------------
template <typename OutT>
__device__ __forceinline__ void gemm128_body(const bf16* __restrict__ A,
                                             const bf16* __restrict__ B,
                                             OutT* __restrict__ C,
                                             int bx, int by) {
  __shared__ bf16 As[2][128 * 64];   // [buf][half*4096 + row*32 + col]
  __shared__ bf16 Bs[2][128 * 64];

  const int tid = threadIdx.x;
  const int wave = tid >> 6, lane = tid & 63;
  const int quad = lane >> 4, l16 = lane & 15;
  const int rowBase = by * 128;
  const int colBase = bx * 128;
  const int waveM = (wave >> 1) * 64, waveN = (wave & 1) * 64;

  // staging map: thread t covers global row t/4, cols (t&3)*8 .. +7
  const int sr = tid >> 2;
  const int sc = (tid & 3) * 8;
  const bf16* Ag0 = A + (size_t)(rowBase + sr) * 1024 + sc;   // rows 0..63
  const bf16* Ag1 = Ag0 + (size_t)64 * 1024;                  // rows 64..127
  const bf16* Bg0 = B + (size_t)(colBase + sr) * 1024 + sc;
  const bf16* Bg1 = Bg0 + (size_t)64 * 1024;

  const int woff = wave * 1024;  // byte offset of this wave's 16-row slab

  auto issue = [&](int k0, int p) {
    char* aB = (char*)As[p] + woff;
    char* bB = (char*)Bs[p] + woff;
    global_to_lds16(Ag0 + k0,      aB);             // half0 rows 0..63
    global_to_lds16(Ag1 + k0,      aB + 4096);      // half0 rows 64..127
    global_to_lds16(Ag0 + k0 + 32, aB + 8192);      // half1 rows 0..63
    global_to_lds16(Ag1 + k0 + 32, aB + 12288);     // half1 rows 64..127
    global_to_lds16(Bg0 + k0,      bB);
    global_to_lds16(Bg1 + k0,      bB + 4096);
    global_to_lds16(Bg0 + k0 + 32, bB + 8192);
    global_to_lds16(Bg1 + k0 + 32, bB + 12288);
  };

  f32x4 acc[4][4] = {};

  issue(0, 0);
  int p = 0;
#pragma unroll 1
  for (int k0 = 0; k0 < 1024; k0 += 64, p ^= 1) {
    __syncthreads();                 // drains loads for tile k0 (buf p)
    if (k0 + 64 < 1024) issue(k0 + 64, p ^ 1);   // prefetch into other buf
#pragma unroll
    for (int kk = 0; kk < 2; kk++) {
      const bf16* base = As[p] + kk * 4096;
      const bf16* baseB = Bs[p] + kk * 4096;
      bf16x8 af[4], bfr[4];
#pragma unroll
      for (int mi = 0; mi < 4; mi++)
        af[mi] = *(const bf16x8*)(base + (waveM + mi * 16 + l16) * 32 + quad * 8);
#pragma unroll
      for (int ni = 0; ni < 4; ni++)
        bfr[ni] = *(const bf16x8*)(baseB + (waveN + ni * 16 + l16) * 32 + quad * 8);
#pragma unroll
      for (int mi = 0; mi < 4; mi++)
#pragma unroll
        for (int ni = 0; ni < 4; ni++)
          acc[mi][ni] = __builtin_amdgcn_mfma_f32_16x16x32_bf16(af[mi], bfr[ni],
                                                                acc[mi][ni], 0, 0, 0);
    }
  }

  OutT* Cb = C + (size_t)(rowBase + waveM) * 1024 + colBase + waveN;
#pragma unroll
  for (int mi = 0; mi < 4; mi++)
#pragma unroll
    for (int ni = 0; ni < 4; ni++)
#pragma unroll
      for (int r = 0; r < 4; r++)
        Cb[(size_t)(mi * 16 + quad * 4 + r) * 1024 + ni * 16 + l16] =
            (OutT)acc[mi][ni][r];
}

// ---------------------------------------------------------------------------
// 128x64-tile NT GEMM body (R6 WIN): gemm128_body with N-extent halved.
// 48 KB LDS -> 3 blocks/CU; L3/L4 get 128 blocks of coverage. Bit-identical
// accumulation chain to gemm128_body.
// ---------------------------------------------------------------------------
template <typename OutT>
__device__ __forceinline__ void gemm128x64_body(const bf16* __restrict__ A,
                                                const bf16* __restrict__ B,
                                                OutT* __restrict__ C,
                                                int bx, int by) {
  __shared__ bf16 As[2][128 * 64];   // 16 KB per buffer (unchanged)
  __shared__ bf16 Bs[2][64 * 64];    // 8 KB per buffer

  const int tid = threadIdx.x;
  const int wave = tid >> 6, lane = tid & 63;
  const int quad = lane >> 4, l16 = lane & 15;
  const int rowBase = by * 128;
  const int colBase = bx * 64;
  const int waveM = (wave >> 1) * 64;   // 0,64
  const int waveN = (wave & 1) * 32;    // 0,32

  const int sr = tid >> 2;
  const int sc = (tid & 3) * 8;
  const bf16* Ag0 = A + (size_t)(rowBase + sr) * 1024 + sc;   // rows 0..63
  const bf16* Ag1 = Ag0 + (size_t)64 * 1024;                  // rows 64..127
  const bf16* Bg0 = B + (size_t)(colBase + sr) * 1024 + sc;   // rows 0..63

  const int woff = wave * 1024;

  auto issue = [&](int k0, int p) {
    char* aB = (char*)As[p] + woff;
    char* bB = (char*)Bs[p] + woff;
    global_to_lds16(Ag0 + k0,      aB);             // half0 rows 0..63
    global_to_lds16(Ag1 + k0,      aB + 4096);      // half0 rows 64..127
    global_to_lds16(Ag0 + k0 + 32, aB + 8192);      // half1 rows 0..63
    global_to_lds16(Ag1 + k0 + 32, aB + 12288);     // half1 rows 64..127
    global_to_lds16(Bg0 + k0,      bB);             // half0 rows 0..63
    global_to_lds16(Bg0 + k0 + 32, bB + 4096);      // half1 rows 0..63
  };

  f32x4 acc[4][2] = {};

  issue(0, 0);
  int p = 0;
#pragma unroll 1
  for (int k0 = 0; k0 < 1024; k0 += 64, p ^= 1) {
    __syncthreads();
    if (k0 + 64 < 1024) issue(k0 + 64, p ^ 1);
#pragma unroll
    for (int kk = 0; kk < 2; kk++) {
      const bf16* base = As[p] + kk * 4096;
      const bf16* baseB = Bs[p] + kk * 2048;
      bf16x8 af[4], bfr[2];
#pragma unroll
      for (int mi = 0; mi < 4; mi++)
        af[mi] = *(const bf16x8*)(base + (waveM + mi * 16 + l16) * 32 + quad * 8);
#pragma unroll
      for (int ni = 0; ni < 2; ni++)
        bfr[ni] = *(const bf16x8*)(baseB + (waveN + ni * 16 + l16) * 32 + quad * 8);
#pragma unroll
      for (int mi = 0; mi < 4; mi++)
#pragma unroll
        for (int ni = 0; ni < 2; ni++)
          acc[mi][ni] = __builtin_amdgcn_mfma_f32_16x16x32_bf16(af[mi], bfr[ni],
                                                                acc[mi][ni], 0, 0, 0);
    }
  }

  OutT* Cb = C + (size_t)(rowBase + waveM) * 1024 + colBase + waveN;
#pragma unroll
  for (int mi = 0; mi < 4; mi++)
#pragma unroll
    for (int ni = 0; ni < 2; ni++)
#pragma unroll
      for (int r = 0; r < 4; r++)
        Cb[(size_t)(mi * 16 + quad * 4 + r) * 1024 + ni * 16 + l16] =
            (OutT)acc[mi][ni][r];
}

// ---------------------------------------------------------------------------
// SPLIT-K 256x128-tile NT GEMM half, BK=32, ping-pong LDS (48 KB -> with 512
// blocks this runs 2 blocks/CU). Each block accumulates K in [kbeg,kbeg+512)
// (ascending, fp32) and atomicAdds its partial into C (fp32, pre-zeroed).
//
// Rationale (R0/R7/R8 post-mortem): 2-phase bodies deliver ~28-30 GB/s/CU of
// staging only at >=2 resident blocks/CU (R0-final: 256 MB -> 40 us
// saturated; R7: 192 MB @ 1 blk/CU -> still 40 us, latency-exposed; R8 pipe
// could not substitute). Split-K doubles the grid to 512 -> 2 blk/CU at the
// 256x128 tile's 24 B/elem -> 192 MB / ~7.1 TB/s ~ 27 us + atomic epilogue.
//
// Staging + XOR-granule swizzle map identical to the PASSING R8 run:
// LDS [row][32] bf16, granule g holds global granule g^((row>>1)&3); linear
// LDS dest + inverse-swizzled global source (rule 21); reads XOR with
// (l16>>1)&3 -> 2-way bank aliasing = free. Per-half accumulation chain is
// bit-identical to the corresponding half of the R7 BK=64 chain; halves
// combine by one order-independent fp32 add (atomicAdd).
// ---------------------------------------------------------------------------
__device__ __forceinline__ void gemm256x128_splitk(const bf16* __restrict__ A,
                                                   const bf16* __restrict__ B,
                                                   float* __restrict__ C,
                                                   int bx, int by, int kbeg) {
  __shared__ bf16 As[2][256 * 32];   // 16 KB per buffer
  __shared__ bf16 Bs[2][128 * 32];   // 8 KB per buffer

  const int tid = threadIdx.x;            // 0..511
  const int wave = tid >> 6, lane = tid & 63;
  const int quad = lane >> 4, l16 = lane & 15;
  const int rowBase = by * 256;
  const int colBase = bx * 128;
  const int waveM = (wave >> 1) * 64;     // 0,64,128,192
  const int waveN = (wave & 1) * 64;      // 0,64

  // staging: one call = 512 thr x 16B = 8 KB = 128 rows of 64 B.
  // thread t -> row t>>2, source granule (t&3)^((t>>3)&3)  (inverse swizzle;
  // (row>>1)&3 == (t>>3)&3).
  const int sr = tid >> 2;                              // 0..127
  const int sg = ((tid & 3) ^ ((tid >> 3) & 3)) << 3;   // bf16 offset
  const bf16* Ag = A + (size_t)(rowBase + sr) * 1024 + sg;
  const bf16* Bg = B + (size_t)(colBase + sr) * 1024 + sg;
  const int woff = wave * 1024;           // wave's 1 KB slab within a call

  auto issue = [&](int k0, int p) {
    char* aB = (char*)As[p] + woff;
    char* bB = (char*)Bs[p] + woff;
    global_to_lds16(Ag + k0, aB);                             // A rows 0..127
    global_to_lds16(Ag + k0 + (size_t)128 * 1024, aB + 8192); // A rows 128..255
    global_to_lds16(Bg + k0, bB);                             // B rows 0..127
  };

  f32x4 acc[4][4] = {};

  issue(kbeg, 0);
  int p = 0;
  const int swz = (l16 >> 1) & 3;
#pragma unroll 1
  for (int i = 0; i < 16; ++i, p ^= 1) {
    __syncthreads();                 // drains loads for sub-tile i (buf p)
    if (i + 1 < 16) issue(kbeg + (i + 1) * 32, p ^ 1);
    const bf16* bA = As[p];
    const bf16* bB = Bs[p];
    bf16x8 af[4], bfr[4];
#pragma unroll
    for (int mi = 0; mi < 4; mi++) {
      const int row = waveM + mi * 16 + l16;
      af[mi] = *(const bf16x8*)(bA + row * 32 + ((quad ^ swz) << 3));
    }
#pragma unroll
    for (int ni = 0; ni < 4; ni++) {
      const int row = waveN + ni * 16 + l16;
      bfr[ni] = *(const bf16x8*)(bB + row * 32 + ((quad ^ swz) << 3));
    }
#pragma unroll
    for (int mi = 0; mi < 4; mi++)
#pragma unroll
      for (int ni = 0; ni < 4; ni++)
        acc[mi][ni] = __builtin_amdgcn_mfma_f32_16x16x32_bf16(af[mi], bfr[ni],
                                                              acc[mi][ni], 0, 0, 0);
  }

  float* Cb = C + (size_t)(rowBase + waveM) * 1024 + colBase + waveN;
#pragma unroll
  for (int mi = 0; mi < 4; mi++)
#pragma unroll
    for (int ni = 0; ni < 4; ni++)
#pragma unroll
      for (int r = 0; r < 4; r++)
        atomicAdd(&Cb[(size_t)(mi * 16 + quad * 4 + r) * 1024 + ni * 16 + l16],
                  acc[mi][ni][r]);
}

// ---------------------------------------------------------------------------
// fused prep kernel (unchanged R0). Flat grid of 5120 independent blocks.
// ---------------------------------------------------------------------------
struct PrepArgs {
  const float* cvt_src[5]; bf16* cvt_dst[5];
  const float* tr_src[6];  bf16* tr_dst[6];
  const float* Wdec; const int* praw; bf16* Gbf;
};

__global__ __launch_bounds__(256) void prep_all(PrepArgs p) {
  __shared__ alignas(16) char smem[64 * 65 * 2];
  const int b = blockIdx.x;
  const int tid = threadIdx.x;

  if (b < 2560) {  // ---- convert row-major W ----
    const int m = b >> 9, blk = b & 511;
    const float* __restrict__ src = p.cvt_src[m];
    bf16* __restrict__ dst = p.cvt_dst[m];
    const int i = (blk * 256 + tid) * 8;
    float4 a = *(const float4*)(src + i);
    float4 c = *(const float4*)(src + i + 4);
    bf16x8 o;
    o[0] = (bf16)a.x; o[1] = (bf16)a.y; o[2] = (bf16)a.z; o[3] = (bf16)a.w;
    o[4] = (bf16)c.x; o[5] = (bf16)c.y; o[6] = (bf16)c.z; o[7] = (bf16)c.w;
    *(bf16x8*)(dst + i) = o;
  } else if (b < 4096) {  // ---- transpose+convert W ----
    const int t = b - 2560;
    const int m = t >> 8, r = t & 255;
    const float* __restrict__ src = p.tr_src[m];
    bf16* __restrict__ dst = p.tr_dst[m];
    bf16(*tile)[65] = reinterpret_cast<bf16(*)[65]>(smem);
    const int bx = (r & 15) * 64;
    const int by = (r >> 4) * 64;
    const int tx = tid & 63;
    const int ty4 = tid >> 6;
#pragma unroll
    for (int rr = 0; rr < 16; rr++) {
      int row = ty4 * 16 + rr;
      tile[row][tx] = (bf16)src[(size_t)(by + row) * 1024 + bx + tx];
    }
    __syncthreads();
#pragma unroll
    for (int rr = 0; rr < 16; rr++) {
      int row = ty4 * 16 + rr;
      dst[(size_t)(bx + row) * 1024 + by + tx] = tile[tx][row];
    }
  } else {  // ---- G build: G[j,d] = sum_{k: perm[k]==d} W_dec[j,k] ----
    const int j = b - 4096;
    float* row = (float*)smem;
    int* perm_l = (int*)(smem + 4096);
    int* nzp = (int*)(smem + 4096 + 1024);
#pragma unroll
    for (int c = 0; c < 4; c++) row[tid * 4 + c] = 0.f;
    if (tid == 0) *nzp = 0;
    __syncthreads();
    // int64 little-endian perm has all-zero high words.
    if (tid < 128 && p.praw[2 * tid + 1] != 0) atomicOr(nzp, 1);
    __syncthreads();
    const int is64 = (*nzp == 0);
    perm_l[tid] = is64 ? p.praw[2 * tid] : p.praw[tid];
    __syncthreads();
    atomicAdd(&row[perm_l[tid]], p.Wdec[(size_t)j * 256 + tid]);
    __syncthreads();
#pragma unroll
    for (int c = 0; c < 4; c++)
      p.Gbf[(size_t)j * 1024 + tid * 4 + c] = (bf16)row[tid * 4 + c];
  }
}

// ---------------------------------------------------------------------------
// Tree-level kernel (unchanged R0): blocks [0, nG*64) do batched 128x128-tile
// NT GEMMs with XCD-aware tile swizzle; blocks >= nG*64 each convert EIGHT
// 2048-float x-units fp32->bf16.
// ---------------------------------------------------------------------------
struct TreeArgs {
  const bf16* A[6]; const bf16* B[6]; bf16* C[6];
  int nG;
  const float* x; bf16* xbf; int ubase;
  float* zout; int zbase;   // out-zeroing filler (L3/L4 only)
};

__global__ __launch_bounds__(256) void tree_level(TreeArgs a) {
  const int b = blockIdx.x;
  const int gBlocks = a.nG * 64;
  if (b < gBlocks) {
    const int z = b >> 6, t = b & 63;
    int bx, by;
    tile8x8_swizzle(t, bx, by);
    gemm128_body<bf16>(a.A[z], a.B[z], a.C[z], bx, by);
  } else {
    const int u0 = a.ubase + (b - gBlocks) * 8;
#pragma unroll
    for (int u = 0; u < 8; u++) {
      const int i = (u0 + u) * 2048 + (int)threadIdx.x * 8;
      float4 v0 = *(const float4*)(a.x + i);
      float4 v1 = *(const float4*)(a.x + i + 4);
      bf16x8 o;
      o[0] = (bf16)v0.x; o[1] = (bf16)v0.y; o[2] = (bf16)v0.z; o[3] = (bf16)v0.w;
      o[4] = (bf16)v1.x; o[5] = (bf16)v1.y; o[6] = (bf16)v1.z; o[7] = (bf16)v1.w;
      *(bf16x8*)(a.xbf + i) = o;
    }
  }
}

// ---------------------------------------------------------------------------
// Half-N tree-level kernel for L3/L4 (R6 WIN): blocks [0,128) do one 1024^2
// NT GEMM as 128x64 tiles; blocks [128,192) do x-convert filler; blocks
// [192,256) zero 256 KB of `out` each (64 blocks x 64 KFloats = 16 MB per
// level; both levels together zero the full 32 MB before the split-K final
// atomicAdds into it). Zeroing runs on otherwise-idle CUs, hidden under the
// ~13 us GEMM window.
// ---------------------------------------------------------------------------
__global__ __launch_bounds__(256) void tree_level_hn(TreeArgs a) {
  const int b = blockIdx.x;
  if (b < 128) {
    gemm128x64_body<bf16>(a.A[0], a.B[0], a.C[0], b >> 3, b & 7);
  } else if (b < 192) {
    const int u0 = a.ubase + (b - 128) * 8;
#pragma unroll
    for (int u = 0; u < 8; u++) {
      const int i = (u0 + u) * 2048 + (int)threadIdx.x * 8;
      float4 v0 = *(const float4*)(a.x + i);
      float4 v1 = *(const float4*)(a.x + i + 4);
      bf16x8 o;
      o[0] = (bf16)v0.x; o[1] = (bf16)v0.y; o[2] = (bf16)v0.z; o[3] = (bf16)v0.w;
      o[4] = (bf16)v1.x; o[5] = (bf16)v1.y; o[6] = (bf16)v1.z; o[7] = (bf16)v1.w;
      *(bf16x8*)(a.xbf + i) = o;
    }
  } else {
    // zero 256 KB of out: block covers 65536 floats, coalesced float4 stores
    float4* o4 = (float4*)(a.zout + (size_t)(a.zbase + (b - 192)) * 65536);
    const float4 z4 = {0.f, 0.f, 0.f, 0.f};
#pragma unroll
    for (int u = 0; u < 64; u++)
      o4[u * 256 + (int)threadIdx.x] = z4;
  }
}

// ---------------------------------------------------------------------------
// Final: out += x * F^T (split-K), fp32 out pre-zeroed by L3/L4. M=8192,
// N=1024, K=1024. 512 blocks = 256 tiles x 2 K-halves -> 2 blocks/CU at
// 48 KB LDS: saturates the ~28-30 GB/s/CU staging rate AT the 256x128
// tile's 24 B/elem (192 MB staged vs 256 MB for 128^2 tiles).
// Tile mapping (t = b&255) identical to R7: XCD k owns by-panels {4k..4k+3}
// + all of F; block t and t+256 (the two K-halves of tile t) land on the
// SAME XCD (t%8 == (t+256)%8) -> no cross-XCD duplication of panel reads.
// ---------------------------------------------------------------------------
__global__ __launch_bounds__(512) void final_gemm(const bf16* __restrict__ A,
                                                  const bf16* __restrict__ B,
                                                  float* __restrict__ C) {
  const int b = blockIdx.x;
  const int t = b & 255;
  const int kbeg = (b >> 8) * 512;
  const int j = t >> 3;
  const int by = (t & 7) * 4 + (j & 3);
  const int bx = j >> 2;
  gemm256x128_splitk(A, B, C, bx, by, kbeg);
}

// ---------------------------------------------------------------------------
// Host launcher.  6 kernels.
// out = x @ (G * W9 * W8 * W8 * W7 * W6 * W5 * W4 * W3 * W2 * W1 * W0)^T
// Tree: P0=G*W9  P1=(W8*W8)^T  P2=W7*W6  P3=(W5*W4)^T  P4=W3*W2  P5=(W1*W0)^T
//       Q0=NT(P0,P1) Q1t=NT(P3,P2) Q2t=NT(P5,P4); R=NT(Q0,Q1t); F=NT(R,Q2t)
//       out = NT(x, F)  via split-K x2 + atomicAdd (out zeroed in L3/L4).
// x convert filler: 2048 units in L1, 1024 in L2, 512 in L3, 512 in L4.
// ---------------------------------------------------------------------------
extern "C" void kernel_launch(void* const* d_in, const int* in_sizes, int n_in,
                              void* d_out, int out_size, void* d_ws, size_t ws_size,
                              hipStream_t stream) {
  const float* x    = (const float*)d_in[0];
  const float* Wsrc = (const float*)d_in[1];   // 10 x 1024 x 1024
  const float* Wdec = (const float*)d_in[2];   // 1024 x 256
  const int*   praw = (const int*)d_in[3];
  float* out = (float*)d_out;

  constexpr size_t MAT  = 1024ull * 1024ull;
  constexpr size_t SLOT = 2ull * 1024 * 1024;  // 2 MiB = one bf16 DxD matrix

  char* ws = (char*)d_ws;
  bf16* Wrm[5];  // W1, W3, W5, W7, W8 (row-major bf16)
  for (int i = 0; i < 5; i++) Wrm[i] = (bf16*)(ws + (size_t)i * SLOT);
  bf16* Wt[6];   // W0^T, W2^T, W4^T, W6^T, W8^T, W9^T
  for (int i = 0; i < 6; i++) Wt[i] = (bf16*)(ws + (size_t)(5 + i) * SLOT);
  bf16* Gbf = (bf16*)(ws + 11 * SLOT);
  bf16* xbf = (bf16*)(ws + 12 * SLOT);         // 8 slots (16 MiB)
  bf16* P[6];
  for (int i = 0; i < 6; i++) P[i] = (bf16*)(ws + (size_t)(20 + i) * SLOT);
  bf16* Q[3];
  for (int i = 0; i < 3; i++) Q[i] = (bf16*)(ws + (size_t)(26 + i) * SLOT);
  bf16* Rb = (bf16*)(ws + 29 * SLOT);
  bf16* Fb = (bf16*)(ws + 30 * SLOT);          // total ws use: 62 MiB

  // 1) fused prep (W converts, W transposes, G)
  PrepArgs pa;
  const int rmIdx[5] = {1, 3, 5, 7, 8};
  for (int i = 0; i < 5; i++) { pa.cvt_src[i] = Wsrc + (size_t)rmIdx[i] * MAT; pa.cvt_dst[i] = Wrm[i]; }
  const int trIdx[6] = {0, 2, 4, 6, 8, 9};
  for (int i = 0; i < 6; i++) { pa.tr_src[i] = Wsrc + (size_t)trIdx[i] * MAT; pa.tr_dst[i] = Wt[i]; }
  pa.Wdec = Wdec; pa.praw = praw; pa.Gbf = Gbf;
  prep_all<<<dim3(5120), 256, 0, stream>>>(pa);

  // 2) L1: 6 GEMMs (384 blocks) + xcvt units [0,2048) as 256 8-unit blocks
  TreeArgs L1{};
  const bf16* l1a[6] = {Gbf, Wt[4], Wrm[3], Wt[2], Wrm[1], Wt[0]};
  const bf16* l1b[6] = {Wt[5], Wrm[4], Wt[3], Wrm[2], Wt[1], Wrm[0]};
  for (int i = 0; i < 6; i++) { L1.A[i] = l1a[i]; L1.B[i] = l1b[i]; L1.C[i] = P[i]; }
  L1.nG = 6; L1.x = x; L1.xbf = xbf; L1.ubase = 0;
  tree_level<<<dim3(384 + 256), 256, 0, stream>>>(L1);

  // 3) L2: Q0=NT(P0,P1) Q1t=NT(P3,P2) Q2t=NT(P5,P4) + xcvt units [2048,3072)
  TreeArgs L2{};
  const bf16* l2a[3] = {P[0], P[3], P[5]};
  const bf16* l2b[3] = {P[1], P[2], P[4]};
  for (int i = 0; i < 3; i++) { L2.A[i] = l2a[i]; L2.B[i] = l2b[i]; L2.C[i] = Q[i]; }
  L2.nG = 3; L2.x = x; L2.xbf = xbf; L2.ubase = 2048;
  tree_level<<<dim3(192 + 128), 256, 0, stream>>>(L2);

  // 4) L3: R = NT(Q0,Q1t) (128 x 128x64 tiles) + xcvt [3072,3584) + zero
  //    first 16 MB of out
  TreeArgs L3{};
  L3.A[0] = Q[0]; L3.B[0] = Q[1]; L3.C[0] = Rb;
  L3.nG = 1; L3.x = x; L3.xbf = xbf; L3.ubase = 3072;
  L3.zout = out; L3.zbase = 0;
  tree_level_hn<<<dim3(256), 256, 0, stream>>>(L3);

  // 5) L4: F = NT(R,Q2t) (128 x 128x64 tiles) + xcvt [3584,4096) + zero
  //    second 16 MB of out
  TreeArgs L4{};
  L4.A[0] = Rb; L4.B[0] = Q[2]; L4.C[0] = Fb;
  L4.nG = 1; L4.x = x; L4.xbf = xbf; L4.ubase = 3584;
  L4.zout = out; L4.zbase = 64;
  tree_level_hn<<<dim3(256), 256, 0, stream>>>(L4);

  // 6) out += NT(x, F), split-K x2, fp32 atomicAdd (512 blocks, 2 blk/CU)
  final_gemm<<<dim3(512), 512, 0, stream>>>(xbf, Fb, out);

  (void)in_sizes; (void)n_in; (void)out_size; (void)ws_size;
}

// Round 10
// 191.339 us; speedup vs baseline: 1.2490x; 1.2490x over previous
//
#include <hip/hip_runtime.h>
#include <stdint.h>
#include <stddef.h>

typedef __bf16 bf16;
typedef __bf16 bf16x8 __attribute__((ext_vector_type(8)));
typedef float f32x4 __attribute__((ext_vector_type(4)));

// ---------------------------------------------------------------------------
// async global->LDS, 16B per lane. LDS dest is wave-uniform base + lane*16.
// ---------------------------------------------------------------------------
__device__ __forceinline__ void global_to_lds16(const void* g, void* l) {
  const __attribute__((address_space(1))) unsigned* gp =
      reinterpret_cast<const __attribute__((address_space(1))) unsigned*>(
          reinterpret_cast<uintptr_t>(g));
  __attribute__((address_space(3))) unsigned* lp =
      reinterpret_cast<__attribute__((address_space(3))) unsigned*>(
          reinterpret_cast<uintptr_t>(l));
  __builtin_amdgcn_global_load_lds(gp, lp, 16, 0, 0);
}

// ---------------------------------------------------------------------------
// XCD-aware tile swizzle for 64-tile (8x8) GEMMs.
// ---------------------------------------------------------------------------
__device__ __forceinline__ void tile8x8_swizzle(int t, int& bx, int& by) {
  bx = (((t >> 3) & 1) << 2) | (t & 3);
  by = (((t >> 4) & 3) << 1) | ((t >> 2) & 1);
}

// ---------------------------------------------------------------------------
// 128x128-tile NT GEMM body, BK=64, PING-PONG double-buffered LDS (64 KB).
// R0 PROVEN BODY (197 us baseline) -- byte-for-byte unchanged.
// ---------------------------------------------------------------------------
template <typename OutT>
__device__ __forceinline__ void gemm128_body(const bf16* __restrict__ A,
                                             const bf16* __restrict__ B,
                                             OutT* __restrict__ C,
                                             int bx, int by) {
  __shared__ bf16 As[2][128 * 64];   // [buf][half*4096 + row*32 + col]
  __shared__ bf16 Bs[2][128 * 64];

  const int tid = threadIdx.x;
  const int wave = tid >> 6, lane = tid & 63;
  const int quad = lane >> 4, l16 = lane & 15;
  const int rowBase = by * 128;
  const int colBase = bx * 128;
  const int waveM = (wave >> 1) * 64, waveN = (wave & 1) * 64;

  // staging map: thread t covers global row t/4, cols (t&3)*8 .. +7
  const int sr = tid >> 2;
  const int sc = (tid & 3) * 8;
  const bf16* Ag0 = A + (size_t)(rowBase + sr) * 1024 + sc;   // rows 0..63
  const bf16* Ag1 = Ag0 + (size_t)64 * 1024;                  // rows 64..127
  const bf16* Bg0 = B + (size_t)(colBase + sr) * 1024 + sc;
  const bf16* Bg1 = Bg0 + (size_t)64 * 1024;

  const int woff = wave * 1024;  // byte offset of this wave's 16-row slab

  auto issue = [&](int k0, int p) {
    char* aB = (char*)As[p] + woff;
    char* bB = (char*)Bs[p] + woff;
    global_to_lds16(Ag0 + k0,      aB);             // half0 rows 0..63
    global_to_lds16(Ag1 + k0,      aB + 4096);      // half0 rows 64..127
    global_to_lds16(Ag0 + k0 + 32, aB + 8192);      // half1 rows 0..63
    global_to_lds16(Ag1 + k0 + 32, aB + 12288);     // half1 rows 64..127
    global_to_lds16(Bg0 + k0,      bB);
    global_to_lds16(Bg1 + k0,      bB + 4096);
    global_to_lds16(Bg0 + k0 + 32, bB + 8192);
    global_to_lds16(Bg1 + k0 + 32, bB + 12288);
  };

  f32x4 acc[4][4] = {};

  issue(0, 0);
  int p = 0;
#pragma unroll 1
  for (int k0 = 0; k0 < 1024; k0 += 64, p ^= 1) {
    __syncthreads();                 // drains loads for tile k0 (buf p)
    if (k0 + 64 < 1024) issue(k0 + 64, p ^ 1);   // prefetch into other buf
#pragma unroll
    for (int kk = 0; kk < 2; kk++) {
      const bf16* base = As[p] + kk * 4096;
      const bf16* baseB = Bs[p] + kk * 4096;
      bf16x8 af[4], bfr[4];
#pragma unroll
      for (int mi = 0; mi < 4; mi++)
        af[mi] = *(const bf16x8*)(base + (waveM + mi * 16 + l16) * 32 + quad * 8);
#pragma unroll
      for (int ni = 0; ni < 4; ni++)
        bfr[ni] = *(const bf16x8*)(baseB + (waveN + ni * 16 + l16) * 32 + quad * 8);
#pragma unroll
      for (int mi = 0; mi < 4; mi++)
#pragma unroll
        for (int ni = 0; ni < 4; ni++)
          acc[mi][ni] = __builtin_amdgcn_mfma_f32_16x16x32_bf16(af[mi], bfr[ni],
                                                                acc[mi][ni], 0, 0, 0);
    }
  }

  OutT* Cb = C + (size_t)(rowBase + waveM) * 1024 + colBase + waveN;
#pragma unroll
  for (int mi = 0; mi < 4; mi++)
#pragma unroll
    for (int ni = 0; ni < 4; ni++)
#pragma unroll
      for (int r = 0; r < 4; r++)
        Cb[(size_t)(mi * 16 + quad * 4 + r) * 1024 + ni * 16 + l16] =
            (OutT)acc[mi][ni][r];
}

// ---------------------------------------------------------------------------
// 128x64-tile NT GEMM body (R6 WIN): gemm128_body with N-extent halved.
// 48 KB LDS -> 3 blocks/CU; single-GEMM stages get 128 blocks of coverage.
// Bit-identical accumulation chain to gemm128_body.
// ---------------------------------------------------------------------------
template <typename OutT>
__device__ __forceinline__ void gemm128x64_body(const bf16* __restrict__ A,
                                                const bf16* __restrict__ B,
                                                OutT* __restrict__ C,
                                                int bx, int by) {
  __shared__ bf16 As[2][128 * 64];   // 16 KB per buffer (unchanged)
  __shared__ bf16 Bs[2][64 * 64];    // 8 KB per buffer

  const int tid = threadIdx.x;
  const int wave = tid >> 6, lane = tid & 63;
  const int quad = lane >> 4, l16 = lane & 15;
  const int rowBase = by * 128;
  const int colBase = bx * 64;
  const int waveM = (wave >> 1) * 64;   // 0,64
  const int waveN = (wave & 1) * 32;    // 0,32

  const int sr = tid >> 2;
  const int sc = (tid & 3) * 8;
  const bf16* Ag0 = A + (size_t)(rowBase + sr) * 1024 + sc;   // rows 0..63
  const bf16* Ag1 = Ag0 + (size_t)64 * 1024;                  // rows 64..127
  const bf16* Bg0 = B + (size_t)(colBase + sr) * 1024 + sc;   // rows 0..63

  const int woff = wave * 1024;

  auto issue = [&](int k0, int p) {
    char* aB = (char*)As[p] + woff;
    char* bB = (char*)Bs[p] + woff;
    global_to_lds16(Ag0 + k0,      aB);             // half0 rows 0..63
    global_to_lds16(Ag1 + k0,      aB + 4096);      // half0 rows 64..127
    global_to_lds16(Ag0 + k0 + 32, aB + 8192);      // half1 rows 0..63
    global_to_lds16(Ag1 + k0 + 32, aB + 12288);     // half1 rows 64..127
    global_to_lds16(Bg0 + k0,      bB);             // half0 rows 0..63
    global_to_lds16(Bg0 + k0 + 32, bB + 4096);      // half1 rows 0..63
  };

  f32x4 acc[4][2] = {};

  issue(0, 0);
  int p = 0;
#pragma unroll 1
  for (int k0 = 0; k0 < 1024; k0 += 64, p ^= 1) {
    __syncthreads();
    if (k0 + 64 < 1024) issue(k0 + 64, p ^ 1);
#pragma unroll
    for (int kk = 0; kk < 2; kk++) {
      const bf16* base = As[p] + kk * 4096;
      const bf16* baseB = Bs[p] + kk * 2048;
      bf16x8 af[4], bfr[2];
#pragma unroll
      for (int mi = 0; mi < 4; mi++)
        af[mi] = *(const bf16x8*)(base + (waveM + mi * 16 + l16) * 32 + quad * 8);
#pragma unroll
      for (int ni = 0; ni < 2; ni++)
        bfr[ni] = *(const bf16x8*)(baseB + (waveN + ni * 16 + l16) * 32 + quad * 8);
#pragma unroll
      for (int mi = 0; mi < 4; mi++)
#pragma unroll
        for (int ni = 0; ni < 2; ni++)
          acc[mi][ni] = __builtin_amdgcn_mfma_f32_16x16x32_bf16(af[mi], bfr[ni],
                                                                acc[mi][ni], 0, 0, 0);
    }
  }

  OutT* Cb = C + (size_t)(rowBase + waveM) * 1024 + colBase + waveN;
#pragma unroll
  for (int mi = 0; mi < 4; mi++)
#pragma unroll
    for (int ni = 0; ni < 2; ni++)
#pragma unroll
      for (int r = 0; r < 4; r++)
        Cb[(size_t)(mi * 16 + quad * 4 + r) * 1024 + ni * 16 + l16] =
            (OutT)acc[mi][ni][r];
}

// ---------------------------------------------------------------------------
// 256x128-tile NT GEMM body (R7 BEST, unchanged). BK=64, ping-pong LDS
// (96 KB), 512 threads = 8 waves (4M x 2N). 24 B staged per output element.
// XOR-granule LDS swizzle (rule 21): linear LDS dest, inverse-swizzled
// global source, swizzled ds_read -> conflict-free. Ascending-K chain.
// ---------------------------------------------------------------------------
template <typename OutT>
__device__ __forceinline__ void gemm256x128_body(const bf16* __restrict__ A,
                                                 const bf16* __restrict__ B,
                                                 OutT* __restrict__ C,
                                                 int bx, int by) {
  __shared__ bf16 As[2][256 * 64];   // 32 KB per buffer
  __shared__ bf16 Bs[2][128 * 64];   // 16 KB per buffer

  const int tid = threadIdx.x;            // 0..511
  const int wave = tid >> 6, lane = tid & 63;
  const int quad = lane >> 4, l16 = lane & 15;
  const int rowBase = by * 256;
  const int colBase = bx * 128;
  const int waveM = (wave >> 1) * 64;     // 0,64,128,192
  const int waveN = (wave & 1) * 64;      // 0,64

  // staging map: one call = 512 threads x 16B = 8 KB = 64 rows of 128 B.
  // lane covers row (call*64 + wave*8 + (lane>>3)); source granule is
  // pre-swizzled: (lane&7) ^ (row&7), and row&7 == lane>>3 here.
  const int srow = tid >> 3;                                  // 0..63
  const int scol = (((tid & 7) ^ ((tid >> 3) & 7)) << 3);     // bf16 offset
  const bf16* Ag = A + (size_t)(rowBase + srow) * 1024 + scol;
  const bf16* Bg = B + (size_t)(colBase + srow) * 1024 + scol;
  const int ldsoff = wave * 1024;         // wave's 1 KB slab within a call

  auto issue = [&](int k0, int p) {
    char* aB = (char*)As[p] + ldsoff;
    char* bB = (char*)Bs[p] + ldsoff;
#pragma unroll
    for (int c = 0; c < 4; c++)           // A: 4 calls x 64 rows
      global_to_lds16(Ag + k0 + (size_t)c * 64 * 1024, aB + c * 8192);
#pragma unroll
    for (int c = 0; c < 2; c++)           // B: 2 calls x 64 rows
      global_to_lds16(Bg + k0 + (size_t)c * 64 * 1024, bB + c * 8192);
  };

  f32x4 acc[4][4] = {};

  issue(0, 0);
  int p = 0;
  const int swz = l16 & 7;
#pragma unroll 1
  for (int k0 = 0; k0 < 1024; k0 += 64, p ^= 1) {
    __syncthreads();                 // drains loads for tile k0 (buf p)
    if (k0 + 64 < 1024) issue(k0 + 64, p ^ 1);   // prefetch into other buf
#pragma unroll
    for (int kk = 0; kk < 2; kk++) {
      bf16x8 af[4], bfr[4];
#pragma unroll
      for (int mi = 0; mi < 4; mi++) {
        const int row = waveM + mi * 16 + l16;
        const int g = ((kk << 2) + quad) ^ swz;   // row&7 == l16&7
        af[mi] = *(const bf16x8*)(As[p] + row * 64 + g * 8);
      }
#pragma unroll
      for (int ni = 0; ni < 4; ni++) {
        const int row = waveN + ni * 16 + l16;
        const int g = ((kk << 2) + quad) ^ swz;
        bfr[ni] = *(const bf16x8*)(Bs[p] + row * 64 + g * 8);
      }
#pragma unroll
      for (int mi = 0; mi < 4; mi++)
#pragma unroll
        for (int ni = 0; ni < 4; ni++)
          acc[mi][ni] = __builtin_amdgcn_mfma_f32_16x16x32_bf16(af[mi], bfr[ni],
                                                                acc[mi][ni], 0, 0, 0);
    }
  }

  OutT* Cb = C + (size_t)(rowBase + waveM) * 1024 + colBase + waveN;
#pragma unroll
  for (int mi = 0; mi < 4; mi++)
#pragma unroll
    for (int ni = 0; ni < 4; ni++)
#pragma unroll
      for (int r = 0; r < 4; r++)
        Cb[(size_t)(mi * 16 + quad * 4 + r) * 1024 + ni * 16 + l16] =
            (OutT)acc[mi][ni][r];
}

// ---------------------------------------------------------------------------
// fused prep kernel (unchanged R0). Flat grid of 5120 independent blocks.
// ---------------------------------------------------------------------------
struct PrepArgs {
  const float* cvt_src[5]; bf16* cvt_dst[5];
  const float* tr_src[6];  bf16* tr_dst[6];
  const float* Wdec; const int* praw; bf16* Gbf;
};

__global__ __launch_bounds__(256) void prep_all(PrepArgs p) {
  __shared__ alignas(16) char smem[64 * 65 * 2];
  const int b = blockIdx.x;
  const int tid = threadIdx.x;

  if (b < 2560) {  // ---- convert row-major W ----
    const int m = b >> 9, blk = b & 511;
    const float* __restrict__ src = p.cvt_src[m];
    bf16* __restrict__ dst = p.cvt_dst[m];
    const int i = (blk * 256 + tid) * 8;
    float4 a = *(const float4*)(src + i);
    float4 c = *(const float4*)(src + i + 4);
    bf16x8 o;
    o[0] = (bf16)a.x; o[1] = (bf16)a.y; o[2] = (bf16)a.z; o[3] = (bf16)a.w;
    o[4] = (bf16)c.x; o[5] = (bf16)c.y; o[6] = (bf16)c.z; o[7] = (bf16)c.w;
    *(bf16x8*)(dst + i) = o;
  } else if (b < 4096) {  // ---- transpose+convert W ----
    const int t = b - 2560;
    const int m = t >> 8, r = t & 255;
    const float* __restrict__ src = p.tr_src[m];
    bf16* __restrict__ dst = p.tr_dst[m];
    bf16(*tile)[65] = reinterpret_cast<bf16(*)[65]>(smem);
    const int bx = (r & 15) * 64;
    const int by = (r >> 4) * 64;
    const int tx = tid & 63;
    const int ty4 = tid >> 6;
#pragma unroll
    for (int rr = 0; rr < 16; rr++) {
      int row = ty4 * 16 + rr;
      tile[row][tx] = (bf16)src[(size_t)(by + row) * 1024 + bx + tx];
    }
    __syncthreads();
#pragma unroll
    for (int rr = 0; rr < 16; rr++) {
      int row = ty4 * 16 + rr;
      dst[(size_t)(bx + row) * 1024 + by + tx] = tile[tx][row];
    }
  } else {  // ---- G build: G[j,d] = sum_{k: perm[k]==d} W_dec[j,k] ----
    const int j = b - 4096;
    float* row = (float*)smem;
    int* perm_l = (int*)(smem + 4096);
    int* nzp = (int*)(smem + 4096 + 1024);
#pragma unroll
    for (int c = 0; c < 4; c++) row[tid * 4 + c] = 0.f;
    if (tid == 0) *nzp = 0;
    __syncthreads();
    // int64 little-endian perm has all-zero high words.
    if (tid < 128 && p.praw[2 * tid + 1] != 0) atomicOr(nzp, 1);
    __syncthreads();
    const int is64 = (*nzp == 0);
    perm_l[tid] = is64 ? p.praw[2 * tid] : p.praw[tid];
    __syncthreads();
    atomicAdd(&row[perm_l[tid]], p.Wdec[(size_t)j * 256 + tid]);
    __syncthreads();
#pragma unroll
    for (int c = 0; c < 4; c++)
      p.Gbf[(size_t)j * 1024 + tid * 4 + c] = (bf16)row[tid * 4 + c];
  }
}

// ---------------------------------------------------------------------------
// Tree-level kernel (unchanged R0): blocks [0, nG*64) do batched 128x128-tile
// NT GEMMs with XCD-aware tile swizzle; blocks >= nG*64 each convert EIGHT
// 2048-float x-units fp32->bf16.
// ---------------------------------------------------------------------------
struct TreeArgs {
  const bf16* A[6]; const bf16* B[6]; bf16* C[6];
  int nG;
  const float* x; bf16* xbf; int ubase;
};

__global__ __launch_bounds__(256) void tree_level(TreeArgs a) {
  const int b = blockIdx.x;
  const int gBlocks = a.nG * 64;
  if (b < gBlocks) {
    const int z = b >> 6, t = b & 63;
    int bx, by;
    tile8x8_swizzle(t, bx, by);
    gemm128_body<bf16>(a.A[z], a.B[z], a.C[z], bx, by);
  } else {
    const int u0 = a.ubase + (b - gBlocks) * 8;
#pragma unroll
    for (int u = 0; u < 8; u++) {
      const int i = (u0 + u) * 2048 + (int)threadIdx.x * 8;
      float4 v0 = *(const float4*)(a.x + i);
      float4 v1 = *(const float4*)(a.x + i + 4);
      bf16x8 o;
      o[0] = (bf16)v0.x; o[1] = (bf16)v0.y; o[2] = (bf16)v0.z; o[3] = (bf16)v0.w;
      o[4] = (bf16)v1.x; o[5] = (bf16)v1.y; o[6] = (bf16)v1.z; o[7] = (bf16)v1.w;
      *(bf16x8*)(a.xbf + i) = o;
    }
  }
}

// ---------------------------------------------------------------------------
// Half-N tree-level kernel, generalized to nG GEMMs (R6-WIN body): blocks
// [0, nG*128) do batched 1024^2 NT GEMMs as 128x64 tiles (z = b>>7,
// t = b&127, bx = t>>3, by = t&7: XCD k owns A-panel k + B). 48 KB LDS ->
// 3 blocks/CU. Blocks >= nG*128 do 8-unit x-convert filler.
// Used for L2 (nG=3: 0.75 -> 1.5 GEMM-blk/CU) and L3/L4 (nG=1).
// ---------------------------------------------------------------------------
__global__ __launch_bounds__(256) void tree_level_hn(TreeArgs a) {
  const int b = blockIdx.x;
  const int gBlocks = a.nG * 128;
  if (b < gBlocks) {
    const int z = b >> 7, t = b & 127;
    gemm128x64_body<bf16>(a.A[z], a.B[z], a.C[z], t >> 3, t & 7);
  } else {
    const int u0 = a.ubase + (b - gBlocks) * 8;
#pragma unroll
    for (int u = 0; u < 8; u++) {
      const int i = (u0 + u) * 2048 + (int)threadIdx.x * 8;
      float4 v0 = *(const float4*)(a.x + i);
      float4 v1 = *(const float4*)(a.x + i + 4);
      bf16x8 o;
      o[0] = (bf16)v0.x; o[1] = (bf16)v0.y; o[2] = (bf16)v0.z; o[3] = (bf16)v0.w;
      o[4] = (bf16)v1.x; o[5] = (bf16)v1.y; o[6] = (bf16)v1.z; o[7] = (bf16)v1.w;
      *(bf16x8*)(a.xbf + i) = o;
    }
  }
}

// ---------------------------------------------------------------------------
// Final: out = x * F^T, fp32 out (R7 BEST, unchanged). M=8192, N=1024,
// K=1024. 256x128 tiles -> 256 blocks = 1 block/CU, zero tail. XCD mapping:
// b%8 = XCD k owns by-panels {4k..4k+3} (2 MB of A) + all of F (2 MB).
// ---------------------------------------------------------------------------
__global__ __launch_bounds__(512) void final_gemm(const bf16* __restrict__ A,
                                                  const bf16* __restrict__ B,
                                                  float* __restrict__ C) {
  const int b = blockIdx.x;
  const int j = b >> 3;
  const int by = (b & 7) * 4 + (j & 3);
  const int bx = j >> 2;
  gemm256x128_body<float>(A, B, C, bx, by);
}

// ---------------------------------------------------------------------------
// Host launcher.  6 kernels.
// out = x @ (G * W9 * W8 * W8 * W7 * W6 * W5 * W4 * W3 * W2 * W1 * W0)^T
// Tree: P0=G*W9  P1=(W8*W8)^T  P2=W7*W6  P3=(W5*W4)^T  P4=W3*W2  P5=(W1*W0)^T
//       Q0=NT(P0,P1) Q1t=NT(P3,P2) Q2t=NT(P5,P4); R=NT(Q0,Q1t); F=NT(R,Q2t)
//       out = NT(x, F).
// Coverage per level (R6/R9 lesson -- every level >= 1 blk/CU, GEMM blocks
// maximized where the level is single-GEMM):
//   L1: 384 GEMM (128^2) + 128 filler = 512 = 2.0/CU
//   L2: 384 GEMM (128x64, was 192 @ 0.75/CU) + 128 filler = 512 = 2.0/CU
//   L3/L4: 128 GEMM (128x64) + 128 filler = 256 = 1.0/CU
// x-convert filler: 1024 units per level (4096 total).
// ---------------------------------------------------------------------------
extern "C" void kernel_launch(void* const* d_in, const int* in_sizes, int n_in,
                              void* d_out, int out_size, void* d_ws, size_t ws_size,
                              hipStream_t stream) {
  const float* x    = (const float*)d_in[0];
  const float* Wsrc = (const float*)d_in[1];   // 10 x 1024 x 1024
  const float* Wdec = (const float*)d_in[2];   // 1024 x 256
  const int*   praw = (const int*)d_in[3];
  float* out = (float*)d_out;

  constexpr size_t MAT  = 1024ull * 1024ull;
  constexpr size_t SLOT = 2ull * 1024 * 1024;  // 2 MiB = one bf16 DxD matrix

  char* ws = (char*)d_ws;
  bf16* Wrm[5];  // W1, W3, W5, W7, W8 (row-major bf16)
  for (int i = 0; i < 5; i++) Wrm[i] = (bf16*)(ws + (size_t)i * SLOT);
  bf16* Wt[6];   // W0^T, W2^T, W4^T, W6^T, W8^T, W9^T
  for (int i = 0; i < 6; i++) Wt[i] = (bf16*)(ws + (size_t)(5 + i) * SLOT);
  bf16* Gbf = (bf16*)(ws + 11 * SLOT);
  bf16* xbf = (bf16*)(ws + 12 * SLOT);         // 8 slots (16 MiB)
  bf16* P[6];
  for (int i = 0; i < 6; i++) P[i] = (bf16*)(ws + (size_t)(20 + i) * SLOT);
  bf16* Q[3];
  for (int i = 0; i < 3; i++) Q[i] = (bf16*)(ws + (size_t)(26 + i) * SLOT);
  bf16* Rb = (bf16*)(ws + 29 * SLOT);
  bf16* Fb = (bf16*)(ws + 30 * SLOT);          // total ws use: 62 MiB

  // 1) fused prep (W converts, W transposes, G)
  PrepArgs pa;
  const int rmIdx[5] = {1, 3, 5, 7, 8};
  for (int i = 0; i < 5; i++) { pa.cvt_src[i] = Wsrc + (size_t)rmIdx[i] * MAT; pa.cvt_dst[i] = Wrm[i]; }
  const int trIdx[6] = {0, 2, 4, 6, 8, 9};
  for (int i = 0; i < 6; i++) { pa.tr_src[i] = Wsrc + (size_t)trIdx[i] * MAT; pa.tr_dst[i] = Wt[i]; }
  pa.Wdec = Wdec; pa.praw = praw; pa.Gbf = Gbf;
  prep_all<<<dim3(5120), 256, 0, stream>>>(pa);

  // 2) L1: 6 GEMMs (384 blocks, 128^2 tiles) + xcvt units [0,1024)
  TreeArgs L1{};
  const bf16* l1a[6] = {Gbf, Wt[4], Wrm[3], Wt[2], Wrm[1], Wt[0]};
  const bf16* l1b[6] = {Wt[5], Wrm[4], Wt[3], Wrm[2], Wt[1], Wrm[0]};
  for (int i = 0; i < 6; i++) { L1.A[i] = l1a[i]; L1.B[i] = l1b[i]; L1.C[i] = P[i]; }
  L1.nG = 6; L1.x = x; L1.xbf = xbf; L1.ubase = 0;
  tree_level<<<dim3(384 + 128), 256, 0, stream>>>(L1);

  // 3) L2: Q0=NT(P0,P1) Q1t=NT(P3,P2) Q2t=NT(P5,P4) as 128x64 tiles
  //    (384 GEMM blocks) + xcvt units [1024,2048)
  TreeArgs L2{};
  const bf16* l2a[3] = {P[0], P[3], P[5]};
  const bf16* l2b[3] = {P[1], P[2], P[4]};
  for (int i = 0; i < 3; i++) { L2.A[i] = l2a[i]; L2.B[i] = l2b[i]; L2.C[i] = Q[i]; }
  L2.nG = 3; L2.x = x; L2.xbf = xbf; L2.ubase = 1024;
  tree_level_hn<<<dim3(384 + 128), 256, 0, stream>>>(L2);

  // 4) L3: R = NT(Q0, Q1t) (128 x 128x64 tiles) + xcvt units [2048,3072)
  TreeArgs L3{};
  L3.A[0] = Q[0]; L3.B[0] = Q[1]; L3.C[0] = Rb;
  L3.nG = 1; L3.x = x; L3.xbf = xbf; L3.ubase = 2048;
  tree_level_hn<<<dim3(128 + 128), 256, 0, stream>>>(L3);

  // 5) L4: F = NT(R, Q2t) (128 x 128x64 tiles) + xcvt units [3072,4096)
  TreeArgs L4{};
  L4.A[0] = Rb; L4.B[0] = Q[2]; L4.C[0] = Fb;
  L4.nG = 1; L4.x = x; L4.xbf = xbf; L4.ubase = 3072;
  tree_level_hn<<<dim3(128 + 128), 256, 0, stream>>>(L4);

  // 6) out = NT(x, F), fp32 out (256 blocks of 256x128, R7 best)
  final_gemm<<<dim3(256), 512, 0, stream>>>(xbf, Fb, out);

  (void)in_sizes; (void)n_in; (void)out_size; (void)ws_size;
}